// Round 8
// baseline (131.387 us; speedup 1.0000x reference)
//
#include <hip/hip_runtime.h>
#include <hip/hip_bf16.h>
#include <stdint.h>
#include <stddef.h>

#define B_   16
#define N_   6272     // T*H*W
#define C_   512
#define K_   64
#define NBC  32       // rows per chunk
#define SLICES 32     // 512 blocks = 2/CU exactly
// slices 0..3 process 7 chunks, 4..31 process 6: 4*7 + 28*6 = 196 = 6272/32

#define WKT_BYTES   ((size_t)K_ * C_ * sizeof(uint16_t))          // 64 KB
#define SUMWS_OFF   WKT_BYTES
#define SUMWS_BYTES ((size_t)B_ * K_ * sizeof(float))             // 4 KB
#define PART_OFF    (0x11000u)                                    // 68 KB
#define PART_ELEMS  ((size_t)SLICES * B_ * C_ * K_)               // bf16 elements
#define WS_NEEDED   (PART_OFF + PART_ELEMS * sizeof(uint16_t))    // ~33.6 MB

#define AP 40        // assgnT pitch in u16 (80B rows: 16B-aligned, conflict ~8-way not 32)

typedef float f32x4 __attribute__((ext_vector_type(4)));
typedef short bf16x8 __attribute__((ext_vector_type(8)));
typedef uint32_t u32x2 __attribute__((ext_vector_type(2)));

__device__ __forceinline__ uint32_t cvt2(float lo, float hi) {
    __hip_bfloat162 h = __float22bfloat162_rn(float2{lo, hi});
    union { __hip_bfloat162 h; uint32_t u; } v; v.h = h;
    return v.u;
}
__device__ __forceinline__ short f32_bf16(float f) {
    union { float f; uint32_t u; } v; v.f = f;
    return (short)((v.u + 0x7FFFu + ((v.u >> 16) & 1u)) >> 16);  // RNE
}
__device__ __forceinline__ float bf16_f32(uint16_t u) {
    union { uint32_t u; float f; } v; v.u = (uint32_t)u << 16;
    return v.f;
}

// LDS-only barrier: drains lgkm (incl. ds_add) but leaves global loads in
// flight. Memory clobbers also fence LICM for per-chunk bq reloads.
__device__ __forceinline__ void bar_lds() {
    asm volatile("s_waitcnt lgkmcnt(0)" ::: "memory");
    __builtin_amdgcn_s_barrier();
    asm volatile("" ::: "memory");
    __builtin_amdgcn_sched_barrier(0);
}

// swizzled LDS byte offset of bf16 element x[n][c]:
//   byte = (n*1024 + c*2) ^ ((n&7)<<4) ^ (((n>>3)&1)<<6)

// ---- prep: WkT[k][c] = bf16(kernel[c][k]); also zeroes sum_ws ----
__global__ void prep_wkt(const float* __restrict__ kern, uint16_t* __restrict__ wkt,
                         float* __restrict__ sum_ws) {
    int idx = blockIdx.x * blockDim.x + threadIdx.x;   // 0..32767
    int k = idx >> 9, c = idx & 511;
    wkt[idx] = (uint16_t)f32_bf16(kern[c * K_ + k]);
    if (idx < B_ * K_) sum_ws[idx] = 0.f;
}

// ---- main fused kernel: 8 waves, dbuf LDS, NBC=32, 3-barrier chunk (R8) ----
// launch_bounds(512,2): empirically 128-VGPR budget & 2 blocks/CU on this
// toolchain (R3: (512,4) forced 64 VGPR -> scratch spill disaster).
// R8: GEMM1 exchange via ds_add_f32 into zeroed red1[32][65] (both C-halves
// accumulate); softmax fully in-wave (lane=cluster, 6-level shfl row-sum),
// eliminating B2 + the red[] round-trip. assgnT pitch 40 (conflict fix).
// setprio(1) around MFMA clusters (T5).
// Ordering proof: zero(t) < B0(t) < ds_adds(t) < B1(t) < reads(t) < B3(t)
// < zero(t+1) — every hazard pair is barrier-separated.
template <bool STORE_PARTIALS>
__global__ __launch_bounds__(512, 2)
void vlad_main(const float* __restrict__ x, const uint16_t* __restrict__ wkt,
               const float* __restrict__ bias, float* __restrict__ out,
               float* __restrict__ sum_ws, uint16_t* __restrict__ partials)
{
    const int b = blockIdx.x, slice = blockIdx.y;
    const int cbase = 6 * slice + (slice < 4 ? slice : 4);   // chunk base
    const int nch   = 6 + (slice < 4 ? 1 : 0);               // chunks this block
    const int tid = threadIdx.x;
    const int w    = tid >> 6;       // wave 0..7
    const int lane = tid & 63;
    const int g = lane & 15, q = lane >> 4;
    const int wr = w >> 2;           // C-half for GEMM1
    const int wc = w & 3;            // cluster group for GEMM1

    // xs FIRST: tr-read asm assumes LDS offset 0 for xs
    __shared__ __align__(16) uint8_t  xs[2][NBC * 1024];   // 2 x 32KB swizzled bf16
    __shared__ __align__(16) uint16_t assgnT[K_][AP];      // [cluster][row], pitch 80B
    __shared__ __align__(16) float    red1[NBC][65];       // full logits, ds_add target

    const float* xb = x + (size_t)b * N_ * C_;
    const uint16_t* wp = wkt + (size_t)(wc * 16 + g) * C_ + wr * 256 + q * 8;

    f32x4 acc2[4][4];   // [mf: clusters 16mf..][nf: channels w*64+nf*16..]
    #pragma unroll
    for (int i = 0; i < 4; ++i)
        #pragma unroll
        for (int j = 0; j < 4; ++j)
            acc2[i][j] = (f32x4){0.f, 0.f, 0.f, 0.f};

    float sumA = 0.f;
    const float bias_l = bias[lane];   // lane = cluster for softmax

    // ---- prologue: stage first chunk into xs[0] (32KB, 8 x 4KB) ----
    {
        const int nb0 = cbase * NBC;
        float4 s0[8];
        #pragma unroll
        for (int it = 0; it < 8; ++it) {
            int o  = it * 4096 + tid * 8;
            int n  = o >> 10;
            int sw = ((n & 7) << 4) ^ (((n >> 3) & 1) << 6);
            int c0 = ((o & 1023) ^ sw) >> 1;
            s0[it] = *(const float4*)(xb + (size_t)(nb0 + n) * C_ + c0);
        }
        #pragma unroll
        for (int it = 0; it < 8; ++it) {
            int o = it * 4096 + tid * 8;
            u32x2 p; p[0] = cvt2(s0[it].x, s0[it].y); p[1] = cvt2(s0[it].z, s0[it].w);
            *(u32x2*)(&xs[0][0] + o) = p;
        }
    }

    for (int t = 0; t < nch; ++t) {
        const int cur = t & 1, nxt = cur ^ 1;
        const bool hasNext = (t + 1 < nch);
        const int nb2 = (cbase + t + 1) * NBC;

        float4 stg[8];
        auto issue = [&](int it) {
            int o  = it * 4096 + tid * 8;
            int n  = o >> 10;
            int sw = ((n & 7) << 4) ^ (((n >> 3) & 1) << 6);
            int c0 = ((o & 1023) ^ sw) >> 1;
            stg[it] = *(const float4*)(xb + (size_t)(nb2 + n) * C_ + c0);
        };
        auto wr_stg = [&](int it) {
            int o = it * 4096 + tid * 8;
            u32x2 p; p[0] = cvt2(stg[it].x, stg[it].y); p[1] = cvt2(stg[it].z, stg[it].w);
            *(u32x2*)(&xs[nxt][0] + o) = p;
        };

        // bq loads FIRST (L2 ~200cy), then stg0..3 (HBM): GEMM1's bq
        // consumption waits a counted vmcnt that leaves stg in flight.
        bf16x8 bq[8];
        #pragma unroll
        for (int ks = 0; ks < 8; ++ks)
            bq[ks] = *(const bf16x8*)(wp + ks * 32);

        if (hasNext) { issue(0); issue(1); issue(2); issue(3); }

        // ---- zero red1 for this chunk's ds_add exchange (pre-B0: ordered
        // before this chunk's adds by B0; after last chunk's reads by B3(t-1))
        {
            float* r1f = &red1[0][0];
            #pragma unroll
            for (int i = 0; i < 5; ++i) {
                int idx = i * 512 + tid;
                if (idx < NBC * 65) r1f[idx] = 0.f;
            }
        }

        bar_lds();   // B0: xs[cur] visible; red1 zeroed; iter t-1 fully done

        // ---------- GEMM1 (C-split): logits[32 rows][16 clusters] ----------
        f32x4 acc1[2];
        acc1[0] = (f32x4){0.f, 0.f, 0.f, 0.f};
        acc1[1] = (f32x4){0.f, 0.f, 0.f, 0.f};
        __builtin_amdgcn_s_setprio(1);
        #pragma unroll
        for (int ks = 0; ks < 8; ++ks) {
            int off = ((g << 10) + ((wr * 256 + ks * 32 + q * 8) << 1))
                      ^ ((g & 7) << 4) ^ (((g >> 3) & 1) << 6);
            bf16x8 a0 = *(const bf16x8*)(&xs[cur][0] + off);            // rows 0..15
            bf16x8 a1 = *(const bf16x8*)(&xs[cur][0] + off + 16384);    // rows 16..31
            acc1[0] = __builtin_amdgcn_mfma_f32_16x16x32_bf16(a0, bq[ks], acc1[0], 0, 0, 0);
            acc1[1] = __builtin_amdgcn_mfma_f32_16x16x32_bf16(a1, bq[ks], acc1[1], 0, 0, 0);
        }
        __builtin_amdgcn_s_setprio(0);

        if (hasNext) { issue(4); issue(5); issue(6); issue(7); }   // bq dead; regs reused

        // ---------- exchange: both C-halves ds_add their logits ----------
        #pragma unroll
        for (int rg = 0; rg < 2; ++rg)
            #pragma unroll
            for (int r = 0; r < 4; ++r)
                atomicAdd(&red1[rg * 16 + q * 4 + r][wc * 16 + g], acc1[rg][r]);

        bar_lds();   // B1: red1 complete logits ready

        // write stg0..3 into xs[nxt] (counted vmcnt wait; loads issued at top)
        if (hasNext) { wr_stg(0); wr_stg(1); wr_stg(2); wr_stg(3); }

        // ---------- in-wave softmax: wave w owns rows w*4..w*4+3, lane=cluster ----------
        {
            const int wrow = w * 4;
            float ev[4], sv[4];
            #pragma unroll
            for (int r = 0; r < 4; ++r)
                ev[r] = __expf(red1[wrow + r][lane] + bias_l);
            #pragma unroll
            for (int r = 0; r < 4; ++r) {
                float s = ev[r];
                s += __shfl_xor(s, 1);
                s += __shfl_xor(s, 2);
                s += __shfl_xor(s, 4);
                s += __shfl_xor(s, 8);
                s += __shfl_xor(s, 16);
                s += __shfl_xor(s, 32);
                sv[r] = s;
            }
            #pragma unroll
            for (int r = 0; r < 4; ++r) {
                float inv;
                asm("v_rcp_f32 %0, %1" : "=v"(inv) : "v"(sv[r]));
                float a = ev[r] * inv;
                sumA += a;
                assgnT[lane][wrow + r] = (uint16_t)f32_bf16(a);
            }
        }

        // ---------- GEMM2 tr-reads hoisted pre-B3 (read xs[cur], no WAR) ----------
        u32x2 lo[4], hi[4];
        {
            const int nr   = q * 8 + (g >> 2);
            const int swz  = ((nr & 7) << 4) ^ (((nr >> 3) & 1) << 6);
            const int raw0 = (nr << 10) + ((4 * (g & 3)) << 1);
            const int bufb = cur * (NBC * 1024);
            #pragma unroll
            for (int nf = 0; nf < 4; ++nf) {
                int raw = raw0 + ((w * 64 + nf * 16) << 1);
                uint32_t ad1 = (uint32_t)((raw ^ swz) + bufb);
                uint32_t ad2 = ad1 ^ 0x40u;                   // row +4 swizzle flip
                asm volatile("ds_read_b64_tr_b16 %0, %1" : "=v"(lo[nf]) : "v"(ad1));
                asm volatile("ds_read_b64_tr_b16 %0, %1 offset:4096" : "=v"(hi[nf]) : "v"(ad2));
            }
        }
        bar_lds();   // B3: assgnT ready; tr-reads drained

        // ---------- GEMM2: acc2 += assgnT @ x_chunk (full K=32) ----------
        __builtin_amdgcn_s_setprio(1);
        #pragma unroll
        for (int mf = 0; mf < 4; ++mf) {
            bf16x8 afr = *(const bf16x8*)&assgnT[mf * 16 + g][q * 8];
            #pragma unroll
            for (int nf = 0; nf < 4; ++nf) {
                union { struct { u32x2 a, b; } p; bf16x8 v; } fr;
                fr.p.a = lo[nf]; fr.p.b = hi[nf];
                acc2[mf][nf] = __builtin_amdgcn_mfma_f32_16x16x32_bf16(afr, fr.v, acc2[mf][nf], 0, 0, 0);
            }
        }
        __builtin_amdgcn_s_setprio(0);

        // write stg4..7 (loads have had GEMM1-tail + softmax + GEMM2 to land)
        if (hasNext) { wr_stg(4); wr_stg(5); wr_stg(6); wr_stg(7); }
        // next B0 makes xs[nxt] visible
    }

    // ---------- epilogue ----------
    // sumA is per-(lane=cluster) over this wave's rows; combine across waves
    // via red1 rows 0..7 (safe: all waves passed B3(last) after their reads).
    red1[w][lane] = sumA;
    bar_lds();
    if (w == 0) {
        float st = 0.f;
        #pragma unroll
        for (int i = 0; i < 8; ++i) st += red1[i][lane];
        atomicAdd(&sum_ws[b * K_ + lane], st);
    }

    if (STORE_PARTIALS) {
        uint16_t* pb = partials + ((size_t)slice * B_ + b) * ((size_t)C_ * K_);
        #pragma unroll
        for (int mf = 0; mf < 4; ++mf)
            #pragma unroll
            for (int nf = 0; nf < 4; ++nf) {
                f32x4 v = acc2[mf][nf];
                u32x2 p; p[0] = cvt2(v[0], v[1]); p[1] = cvt2(v[2], v[3]);
                int chn = w * 64 + nf * 16 + g;
                int cl  = mf * 16 + q * 4;
                __builtin_nontemporal_store(p, (u32x2*)(pb + (size_t)chn * K_ + cl));
            }
    } else {
        float* ob = out + (size_t)b * K_ * C_;
        #pragma unroll
        for (int mf = 0; mf < 4; ++mf)
            #pragma unroll
            for (int nf = 0; nf < 4; ++nf)
                #pragma unroll
                for (int r = 0; r < 4; ++r) {
                    int cluster = mf * 16 + q * 4 + r;
                    int chn = w * 64 + nf * 16 + g;
                    atomicAdd(&ob[(size_t)cluster * C_ + chn], acc2[mf][nf][r]);
                }
    }
}

// ---- reduce partials + subtract centers + /N (parallel-slice, R7) ----
__global__ void vlad_reduce(const uint16_t* __restrict__ partials,
                            const float* __restrict__ sum_ws,
                            const float* __restrict__ centers,
                            float* __restrict__ out)
{
    const int blk = blockIdx.x;          // (b, chn8-group)
    const int b    = blk >> 6;
    const int chn0 = (blk & 63) * 8;
    const int tid = threadIdx.x;
    const int sg  = tid >> 6;            // slice group 0..3
    const int chl = (tid >> 3) & 7;      // chn local 0..7
    const int cl8 = tid & 7;             // cluster-8 group

    __shared__ float lds[4][64][9];      // [sg][cluster][chn], +1 pad

    float acc[8] = {0,0,0,0,0,0,0,0};
    const uint16_t* p = partials + (size_t)b * ((size_t)C_ * K_)
                      + (size_t)(chn0 + chl) * K_ + cl8 * 8;
    #pragma unroll
    for (int s = 0; s < 8; ++s) {        // slices sg, sg+4, ..., sg+28
        bf16x8 v = *(const bf16x8*)(p + (size_t)(sg + s * 4) * ((size_t)B_ * C_ * K_));
        #pragma unroll
        for (int j = 0; j < 8; ++j)
            acc[j] += bf16_f32((uint16_t)v[j]);
    }
    #pragma unroll
    for (int j = 0; j < 8; ++j)
        lds[sg][cl8 * 8 + j][chl] = acc[j];
    __syncthreads();

    const float inv = 1.0f / (float)N_;
    const int chn = tid & 7;
    const int cl  = tid >> 3;            // 0..31
    #pragma unroll
    for (int cc = cl; cc < 64; cc += 32) {
        float r = (lds[0][cc][chn] + lds[1][cc][chn])
                + (lds[2][cc][chn] + lds[3][cc][chn]);
        r = (r - sum_ws[b * K_ + cc] * centers[(size_t)cc * C_ + chn0 + chn]) * inv;
        out[((size_t)b * K_ + cc) * C_ + chn0 + chn] = r;
    }
}

// ---- final for atomic fallback path ----
__global__ void vlad_final(float* __restrict__ out, const float* __restrict__ sum_ws,
                           const float* __restrict__ centers)
{
    int idx = blockIdx.x * blockDim.x + threadIdx.x;
    int c4 = idx & (C_ / 4 - 1);
    int k  = (idx >> 7) & (K_ - 1);
    int b  = idx >> 13;
    float s = sum_ws[b * K_ + k];
    float4 o  = ((float4*)out)[idx];
    float4 ce = ((const float4*)centers)[k * (C_ / 4) + c4];
    const float inv = 1.0f / (float)N_;
    o.x = (o.x - s * ce.x) * inv;
    o.y = (o.y - s * ce.y) * inv;
    o.z = (o.z - s * ce.z) * inv;
    o.w = (o.w - s * ce.w) * inv;
    ((float4*)out)[idx] = o;
}

extern "C" void kernel_launch(void* const* d_in, const int* in_sizes, int n_in,
                              void* d_out, int out_size, void* d_ws, size_t ws_size,
                              hipStream_t stream)
{
    const float* x       = (const float*)d_in[0];
    const float* kern    = (const float*)d_in[1];
    const float* bias    = (const float*)d_in[2];
    const float* centers = (const float*)d_in[3];
    float* out = (float*)d_out;

    uint16_t* wkt    = (uint16_t*)d_ws;
    float*    sum_ws = (float*)((char*)d_ws + SUMWS_OFF);
    uint16_t* parts  = (uint16_t*)((char*)d_ws + PART_OFF);

    prep_wkt<<<(K_ * C_) / 256, 256, 0, stream>>>(kern, wkt, sum_ws);

    if (ws_size >= WS_NEEDED) {
        vlad_main<true><<<dim3(B_, SLICES), 512, 0, stream>>>(x, wkt, bias, out, sum_ws, parts);
        vlad_reduce<<<B_ * (C_ / 8), 256, 0, stream>>>(parts, sum_ws, centers, out);
    } else {
        hipMemsetAsync(out, 0, sizeof(float) * (size_t)B_ * K_ * C_, stream);
        vlad_main<false><<<dim3(B_, SLICES), 512, 0, stream>>>(x, wkt, bias, out, sum_ws, parts);
        vlad_final<<<(B_ * K_ * C_ / 4) / 256, 256, 0, stream>>>(out, sum_ws, centers);
    }
}

// Round 9
// 78.742 us; speedup vs baseline: 1.6686x; 1.6686x over previous
//
#include <hip/hip_runtime.h>
#include <hip/hip_bf16.h>
#include <stdint.h>
#include <stddef.h>

#define B_   16
#define N_   6272     // T*H*W
#define C_   512
#define K_   64
#define NBC  32       // rows per chunk
#define SLICES 32     // 512 blocks = 2/CU exactly
// slices 0..3 process 7 chunks, 4..31 process 6: 4*7 + 28*6 = 196 = 6272/32

#define WKT_BYTES   ((size_t)K_ * C_ * sizeof(uint16_t))          // 64 KB
#define SUMWS_OFF   WKT_BYTES
#define SUMWS_BYTES ((size_t)B_ * K_ * sizeof(float))             // 4 KB
#define PART_OFF    (0x11000u)                                    // 68 KB
#define PART_ELEMS  ((size_t)SLICES * B_ * C_ * K_)               // bf16 elements
#define WS_NEEDED   (PART_OFF + PART_ELEMS * sizeof(uint16_t))    // ~33.6 MB

#define AP 40        // assgnT pitch in u16 (80B rows, 16B-aligned; breaks the
                     // pitch-64B ~8-bank aliasing of writes AND b128 reads)

typedef float f32x4 __attribute__((ext_vector_type(4)));
typedef short bf16x8 __attribute__((ext_vector_type(8)));
typedef uint32_t u32x2 __attribute__((ext_vector_type(2)));

__device__ __forceinline__ uint32_t cvt2(float lo, float hi) {
    __hip_bfloat162 h = __float22bfloat162_rn(float2{lo, hi});
    union { __hip_bfloat162 h; uint32_t u; } v; v.h = h;
    return v.u;
}
__device__ __forceinline__ short f32_bf16(float f) {
    union { float f; uint32_t u; } v; v.f = f;
    return (short)((v.u + 0x7FFFu + ((v.u >> 16) & 1u)) >> 16);  // RNE
}
__device__ __forceinline__ float bf16_f32(uint16_t u) {
    union { uint32_t u; float f; } v; v.u = (uint32_t)u << 16;
    return v.f;
}

// LDS-only barrier: drains lgkm (ds ops) but leaves global loads in flight.
// Memory clobbers also fence LICM for the per-chunk bq reloads.
__device__ __forceinline__ void bar_lds() {
    asm volatile("s_waitcnt lgkmcnt(0)" ::: "memory");
    __builtin_amdgcn_s_barrier();
    asm volatile("" ::: "memory");
    __builtin_amdgcn_sched_barrier(0);
}

// swizzled LDS byte offset of bf16 element x[n][c]:
//   byte = (n*1024 + c*2) ^ ((n&7)<<4) ^ (((n>>3)&1)<<6)

// ---- prep: WkT[k][c] = bf16(kernel[c][k]); also zeroes sum_ws ----
__global__ void prep_wkt(const float* __restrict__ kern, uint16_t* __restrict__ wkt,
                         float* __restrict__ sum_ws) {
    int idx = blockIdx.x * blockDim.x + threadIdx.x;   // 0..32767
    int k = idx >> 9, c = idx & 511;
    wkt[idx] = (uint16_t)f32_bf16(kern[c * K_ + k]);
    if (idx < B_ * K_) sum_ws[idx] = 0.f;
}

// ---- main fused kernel: 8 waves, dbuf LDS, NBC=32, split-row softmax ----
// launch_bounds(512,2): empirically 128-VGPR budget & 2 blocks/CU on this
// toolchain (R3: (512,4) forced 64 VGPR -> scratch spill disaster).
// R9 (on R7 base; R8's LDS-atomic exchange fully reverted — it cost +52us):
//   1. assgnT pitch 64B -> 80B (AP=40): conflict fix, layout otherwise same.
//   2. phase stagger: co-resident partner blocks (slice s and s+16 land on
//      the same CU under linear dispatch) are phase-locked; slice>=16 sleeps
//      ~2us at entry to anti-phase MFMA/LDS/HBM peaks against its partner.
template <bool STORE_PARTIALS>
__global__ __launch_bounds__(512, 2)
void vlad_main(const float* __restrict__ x, const uint16_t* __restrict__ wkt,
               const float* __restrict__ bias, float* __restrict__ out,
               float* __restrict__ sum_ws, uint16_t* __restrict__ partials)
{
    const int b = blockIdx.x, slice = blockIdx.y;
    const int cbase = 6 * slice + (slice < 4 ? slice : 4);   // chunk base
    const int nch   = 6 + (slice < 4 ? 1 : 0);               // chunks this block
    const int tid = threadIdx.x;
    const int w    = tid >> 6;       // wave 0..7
    const int lane = tid & 63;
    const int g = lane & 15, q = lane >> 4;
    const int wr = w >> 2;           // C-half for GEMM1; row-half for softmax
    const int wc = w & 3;            // cluster group

    // de-phase the second-resident half of the grid (~4800 cy ~= 2us)
    if (slice >= 16) {
        #pragma unroll
        for (int i = 0; i < 5; ++i) __builtin_amdgcn_s_sleep(15);
    }

    // xs FIRST: tr-read asm assumes LDS offset 0 for xs
    __shared__ __align__(16) uint8_t  xs[2][NBC * 1024];   // 2 x 32KB swizzled bf16
    __shared__ __align__(16) uint16_t assgnT[K_][AP];      // [cluster][row], pitch 80B
    __shared__ __align__(16) float    red1a[16][K_];       // rg0 partial logits (C-half1)
    __shared__ __align__(16) float    red1b[16][K_];       // rg1 partial logits (C-half0)
    __shared__ __align__(16) float    red[NBC][4];         // row softmax sums

    const float* xb = x + (size_t)b * N_ * C_;
    const uint16_t* wp = wkt + (size_t)(wc * 16 + g) * C_ + wr * 256 + q * 8;

    f32x4 acc2[4][4];   // [mf: clusters 16mf..][nf: channels w*64+nf*16..]
    #pragma unroll
    for (int i = 0; i < 4; ++i)
        #pragma unroll
        for (int j = 0; j < 4; ++j)
            acc2[i][j] = (f32x4){0.f, 0.f, 0.f, 0.f};

    float sumA = 0.f;
    const float bias_c = bias[wc * 16 + g];

    // ---- prologue: stage first chunk into xs[0] (32KB, 8 x 4KB) ----
    {
        const int nb0 = cbase * NBC;
        float4 s0[8];
        #pragma unroll
        for (int it = 0; it < 8; ++it) {
            int o  = it * 4096 + tid * 8;
            int n  = o >> 10;
            int sw = ((n & 7) << 4) ^ (((n >> 3) & 1) << 6);
            int c0 = ((o & 1023) ^ sw) >> 1;
            s0[it] = *(const float4*)(xb + (size_t)(nb0 + n) * C_ + c0);
        }
        #pragma unroll
        for (int it = 0; it < 8; ++it) {
            int o = it * 4096 + tid * 8;
            u32x2 p; p[0] = cvt2(s0[it].x, s0[it].y); p[1] = cvt2(s0[it].z, s0[it].w);
            *(u32x2*)(&xs[0][0] + o) = p;
        }
    }

    for (int t = 0; t < nch; ++t) {
        const int cur = t & 1, nxt = cur ^ 1;
        const bool hasNext = (t + 1 < nch);
        const int nb2 = (cbase + t + 1) * NBC;

        float4 stg[8];
        auto issue = [&](int it) {
            int o  = it * 4096 + tid * 8;
            int n  = o >> 10;
            int sw = ((n & 7) << 4) ^ (((n >> 3) & 1) << 6);
            int c0 = ((o & 1023) ^ sw) >> 1;
            stg[it] = *(const float4*)(xb + (size_t)(nb2 + n) * C_ + c0);
        };
        auto wr_stg = [&](int it) {
            int o = it * 4096 + tid * 8;
            u32x2 p; p[0] = cvt2(stg[it].x, stg[it].y); p[1] = cvt2(stg[it].z, stg[it].w);
            *(u32x2*)(&xs[nxt][0] + o) = p;
        };

        // bq loads FIRST (L2 ~200cy), then stg0..3 (HBM): GEMM1's bq
        // consumption waits a counted vmcnt that leaves stg in flight.
        bf16x8 bq[8];
        #pragma unroll
        for (int ks = 0; ks < 8; ++ks)
            bq[ks] = *(const bf16x8*)(wp + ks * 32);

        if (hasNext) { issue(0); issue(1); issue(2); issue(3); }

        bar_lds();   // B0: xs[cur] visible; iter t-1 fully done

        // ---------- GEMM1 (C-split): logits[32 rows][16 clusters] ----------
        f32x4 acc1[2];
        acc1[0] = (f32x4){0.f, 0.f, 0.f, 0.f};
        acc1[1] = (f32x4){0.f, 0.f, 0.f, 0.f};
        #pragma unroll
        for (int ks = 0; ks < 8; ++ks) {
            int off = ((g << 10) + ((wr * 256 + ks * 32 + q * 8) << 1))
                      ^ ((g & 7) << 4) ^ (((g >> 3) & 1) << 6);
            bf16x8 a0 = *(const bf16x8*)(&xs[cur][0] + off);            // rows 0..15
            bf16x8 a1 = *(const bf16x8*)(&xs[cur][0] + off + 16384);    // rows 16..31
            acc1[0] = __builtin_amdgcn_mfma_f32_16x16x32_bf16(a0, bq[ks], acc1[0], 0, 0, 0);
            acc1[1] = __builtin_amdgcn_mfma_f32_16x16x32_bf16(a1, bq[ks], acc1[1], 0, 0, 0);
        }

        if (hasNext) { issue(4); issue(5); issue(6); issue(7); }   // bq dead; regs reused

        // ---------- cross-half exchange: each wr group exports the half it
        // won't softmax (wr1 softmaxes rows 16..31 -> exports rg0, and v.v.)
        if (wr == 1) {
            #pragma unroll
            for (int r = 0; r < 4; ++r)
                red1a[q * 4 + r][wc * 16 + g] = acc1[0][r];   // rg0, C-half1
        } else {
            #pragma unroll
            for (int r = 0; r < 4; ++r)
                red1b[q * 4 + r][wc * 16 + g] = acc1[1][r];   // rg1, C-half0
        }
        bar_lds();   // B1

        // write stg0..3 into xs[nxt] (counted vmcnt wait; loads issued at top)
        if (hasNext) { wr_stg(0); wr_stg(1); wr_stg(2); wr_stg(3); }

        // ---------- split-row softmax: wr0 -> rows 0..15, wr1 -> rows 16..31 ----------
        float ev[4];
        {
            const float* rp = (wr == 0) ? &red1a[0][0] : &red1b[0][0];
            const f32x4  ac = (wr == 0) ? acc1[0] : acc1[1];
            #pragma unroll
            for (int r = 0; r < 4; ++r) {
                float tot = ac[r] + rp[(q * 4 + r) * K_ + wc * 16 + g] + bias_c;
                ev[r] = __expf(tot);
                float s = ev[r];
                s += __shfl_xor(s, 1);
                s += __shfl_xor(s, 2);
                s += __shfl_xor(s, 4);
                s += __shfl_xor(s, 8);
                if (g == 0) red[wr * 16 + q * 4 + r][wc] = s;
            }
        }
        bar_lds();   // B2

        #pragma unroll
        for (int r = 0; r < 4; ++r) {
            int row = wr * 16 + q * 4 + r;
            float4 rv = *(const float4*)red[row];
            float s = (rv.x + rv.y) + (rv.z + rv.w);
            float a = ev[r] / s;
            sumA += a;
            assgnT[wc * 16 + g][row] = (uint16_t)f32_bf16(a);
        }

        // ---------- GEMM2 tr-reads hoisted pre-B3: they read xs[cur] (valid
        // since B0, no WAR — staging writes go to xs[nxt]); B3's lgkm drain
        // doubles as their completion wait ----------
        u32x2 lo[4], hi[4];
        {
            const int nr   = q * 8 + (g >> 2);
            const int swz  = ((nr & 7) << 4) ^ (((nr >> 3) & 1) << 6);
            const int raw0 = (nr << 10) + ((4 * (g & 3)) << 1);
            const int bufb = cur * (NBC * 1024);
            #pragma unroll
            for (int nf = 0; nf < 4; ++nf) {
                int raw = raw0 + ((w * 64 + nf * 16) << 1);
                uint32_t ad1 = (uint32_t)((raw ^ swz) + bufb);
                uint32_t ad2 = ad1 ^ 0x40u;                   // row +4 swizzle flip
                asm volatile("ds_read_b64_tr_b16 %0, %1" : "=v"(lo[nf]) : "v"(ad1));
                asm volatile("ds_read_b64_tr_b16 %0, %1 offset:4096" : "=v"(hi[nf]) : "v"(ad2));
            }
        }
        bar_lds();   // B3: assgnT ready; tr-reads drained

        // ---------- GEMM2: acc2 += assgnT @ x_chunk (full K=32) ----------
        // mf-outer: one live A-frag
        #pragma unroll
        for (int mf = 0; mf < 4; ++mf) {
            bf16x8 afr = *(const bf16x8*)&assgnT[mf * 16 + g][q * 8];
            #pragma unroll
            for (int nf = 0; nf < 4; ++nf) {
                union { struct { u32x2 a, b; } p; bf16x8 v; } fr;
                fr.p.a = lo[nf]; fr.p.b = hi[nf];
                acc2[mf][nf] = __builtin_amdgcn_mfma_f32_16x16x32_bf16(afr, fr.v, acc2[mf][nf], 0, 0, 0);
            }
        }

        // write stg4..7 (loads have had GEMM1-tail + softmax + GEMM2 to land)
        if (hasNext) { wr_stg(4); wr_stg(5); wr_stg(6); wr_stg(7); }
        // next B0 makes xs[nxt] visible
    }

    // ---------- epilogue ----------
    {
        float st = sumA;
        st += __shfl_xor(st, 16);
        st += __shfl_xor(st, 32);
        if (q == 0) atomicAdd(&sum_ws[b * K_ + wc * 16 + g], st);
    }

    if (STORE_PARTIALS) {
        uint16_t* pb = partials + ((size_t)slice * B_ + b) * ((size_t)C_ * K_);
        #pragma unroll
        for (int mf = 0; mf < 4; ++mf)
            #pragma unroll
            for (int nf = 0; nf < 4; ++nf) {
                f32x4 v = acc2[mf][nf];
                u32x2 p; p[0] = cvt2(v[0], v[1]); p[1] = cvt2(v[2], v[3]);
                int chn = w * 64 + nf * 16 + g;
                int cl  = mf * 16 + q * 4;
                __builtin_nontemporal_store(p, (u32x2*)(pb + (size_t)chn * K_ + cl));
            }
    } else {
        float* ob = out + (size_t)b * K_ * C_;
        #pragma unroll
        for (int mf = 0; mf < 4; ++mf)
            #pragma unroll
            for (int nf = 0; nf < 4; ++nf)
                #pragma unroll
                for (int r = 0; r < 4; ++r) {
                    int cluster = mf * 16 + q * 4 + r;
                    int chn = w * 64 + nf * 16 + g;
                    atomicAdd(&ob[(size_t)cluster * C_ + chn], acc2[mf][nf][r]);
                }
    }
}

// ---- reduce partials + subtract centers + /N (parallel-slice, R7) ----
__global__ void vlad_reduce(const uint16_t* __restrict__ partials,
                            const float* __restrict__ sum_ws,
                            const float* __restrict__ centers,
                            float* __restrict__ out)
{
    const int blk = blockIdx.x;          // (b, chn8-group)
    const int b    = blk >> 6;
    const int chn0 = (blk & 63) * 8;
    const int tid = threadIdx.x;
    const int sg  = tid >> 6;            // slice group 0..3
    const int chl = (tid >> 3) & 7;      // chn local 0..7
    const int cl8 = tid & 7;             // cluster-8 group

    __shared__ float lds[4][64][9];      // [sg][cluster][chn], +1 pad

    float acc[8] = {0,0,0,0,0,0,0,0};
    const uint16_t* p = partials + (size_t)b * ((size_t)C_ * K_)
                      + (size_t)(chn0 + chl) * K_ + cl8 * 8;
    #pragma unroll
    for (int s = 0; s < 8; ++s) {        // slices sg, sg+4, ..., sg+28
        bf16x8 v = *(const bf16x8*)(p + (size_t)(sg + s * 4) * ((size_t)B_ * C_ * K_));
        #pragma unroll
        for (int j = 0; j < 8; ++j)
            acc[j] += bf16_f32((uint16_t)v[j]);
    }
    #pragma unroll
    for (int j = 0; j < 8; ++j)
        lds[sg][cl8 * 8 + j][chl] = acc[j];
    __syncthreads();

    const float inv = 1.0f / (float)N_;
    const int chn = tid & 7;
    const int cl  = tid >> 3;            // 0..31
    #pragma unroll
    for (int cc = cl; cc < 64; cc += 32) {
        float r = (lds[0][cc][chn] + lds[1][cc][chn])
                + (lds[2][cc][chn] + lds[3][cc][chn]);
        r = (r - sum_ws[b * K_ + cc] * centers[(size_t)cc * C_ + chn0 + chn]) * inv;
        out[((size_t)b * K_ + cc) * C_ + chn0 + chn] = r;
    }
}

// ---- final for atomic fallback path ----
__global__ void vlad_final(float* __restrict__ out, const float* __restrict__ sum_ws,
                           const float* __restrict__ centers)
{
    int idx = blockIdx.x * blockDim.x + threadIdx.x;
    int c4 = idx & (C_ / 4 - 1);
    int k  = (idx >> 7) & (K_ - 1);
    int b  = idx >> 13;
    float s = sum_ws[b * K_ + k];
    float4 o  = ((float4*)out)[idx];
    float4 ce = ((const float4*)centers)[k * (C_ / 4) + c4];
    const float inv = 1.0f / (float)N_;
    o.x = (o.x - s * ce.x) * inv;
    o.y = (o.y - s * ce.y) * inv;
    o.z = (o.z - s * ce.z) * inv;
    o.w = (o.w - s * ce.w) * inv;
    ((float4*)out)[idx] = o;
}

extern "C" void kernel_launch(void* const* d_in, const int* in_sizes, int n_in,
                              void* d_out, int out_size, void* d_ws, size_t ws_size,
                              hipStream_t stream)
{
    const float* x       = (const float*)d_in[0];
    const float* kern    = (const float*)d_in[1];
    const float* bias    = (const float*)d_in[2];
    const float* centers = (const float*)d_in[3];
    float* out = (float*)d_out;

    uint16_t* wkt    = (uint16_t*)d_ws;
    float*    sum_ws = (float*)((char*)d_ws + SUMWS_OFF);
    uint16_t* parts  = (uint16_t*)((char*)d_ws + PART_OFF);

    prep_wkt<<<(K_ * C_) / 256, 256, 0, stream>>>(kern, wkt, sum_ws);

    if (ws_size >= WS_NEEDED) {
        vlad_main<true><<<dim3(B_, SLICES), 512, 0, stream>>>(x, wkt, bias, out, sum_ws, parts);
        vlad_reduce<<<B_ * (C_ / 8), 256, 0, stream>>>(parts, sum_ws, centers, out);
    } else {
        hipMemsetAsync(out, 0, sizeof(float) * (size_t)B_ * K_ * C_, stream);
        vlad_main<false><<<dim3(B_, SLICES), 512, 0, stream>>>(x, wkt, bias, out, sum_ws, parts);
        vlad_final<<<(B_ * K_ * C_ / 4) / 256, 256, 0, stream>>>(out, sum_ws, centers);
    }
}

// Round 10
// 78.208 us; speedup vs baseline: 1.6800x; 1.0068x over previous
//
#include <hip/hip_runtime.h>
#include <hip/hip_bf16.h>
#include <stdint.h>
#include <stddef.h>

#define B_   16
#define N_   6272     // T*H*W
#define C_   512
#define K_   64
#define NBC  32       // rows per chunk
#define SLICES 32     // 512 blocks = 2/CU exactly
// slices 0..3 process 7 chunks, 4..31 process 6: 4*7 + 28*6 = 196 = 6272/32

#define WKT_BYTES   ((size_t)K_ * C_ * sizeof(uint16_t))          // 64 KB
#define SUMWS_OFF   WKT_BYTES
#define SUMWS_BYTES ((size_t)B_ * K_ * sizeof(float))             // 4 KB
#define PART_OFF    (0x11000u)                                    // 68 KB
#define PART_ELEMS  ((size_t)SLICES * B_ * C_ * K_)               // bf16 elements
#define WS_NEEDED   (PART_OFF + PART_ELEMS * sizeof(uint16_t))    // ~33.6 MB

#define AP 40        // assgnT pitch in u16 (80B rows, 16B-aligned; breaks the
                     // pitch-64B ~8-bank aliasing of writes AND b128 reads)

typedef float f32x4 __attribute__((ext_vector_type(4)));
typedef short bf16x8 __attribute__((ext_vector_type(8)));
typedef uint32_t u32x2 __attribute__((ext_vector_type(2)));

__device__ __forceinline__ uint32_t cvt2(float lo, float hi) {
    __hip_bfloat162 h = __float22bfloat162_rn(float2{lo, hi});
    union { __hip_bfloat162 h; uint32_t u; } v; v.h = h;
    return v.u;
}
__device__ __forceinline__ short f32_bf16(float f) {
    union { float f; uint32_t u; } v; v.f = f;
    return (short)((v.u + 0x7FFFu + ((v.u >> 16) & 1u)) >> 16);  // RNE
}
__device__ __forceinline__ float bf16_f32(uint16_t u) {
    union { uint32_t u; float f; } v; v.u = (uint32_t)u << 16;
    return v.f;
}

// LDS-only barrier: drains lgkm (ds ops) but leaves global loads in flight.
// Memory clobbers also fence LICM for the per-chunk bq reloads.
__device__ __forceinline__ void bar_lds() {
    asm volatile("s_waitcnt lgkmcnt(0)" ::: "memory");
    __builtin_amdgcn_s_barrier();
    asm volatile("" ::: "memory");
    __builtin_amdgcn_sched_barrier(0);
}

// swizzled LDS byte offset of bf16 element x[n][c]:
//   byte = (n*1024 + c*2) ^ ((n&7)<<4) ^ (((n>>3)&1)<<6)

// ---- prep: WkT[k][c] = bf16(kernel[c][k]); also zeroes sum_ws ----
__global__ void prep_wkt(const float* __restrict__ kern, uint16_t* __restrict__ wkt,
                         float* __restrict__ sum_ws) {
    int idx = blockIdx.x * blockDim.x + threadIdx.x;   // 0..32767
    int k = idx >> 9, c = idx & 511;
    wkt[idx] = (uint16_t)f32_bf16(kern[c * K_ + k]);
    if (idx < B_ * K_) sum_ws[idx] = 0.f;
}

// ---- main fused kernel: 8 waves, dbuf LDS, NBC=32, split-row softmax ----
// launch_bounds(512,2): empirically 128-VGPR budget & 2 blocks/CU on this
// toolchain (R3: (512,4) forced 64 VGPR -> scratch spill disaster).
// R10 (consolidation on R9): v_rcp in softmax (R8-proven-correct), T5
// setprio around MFMA clusters. Structure frozen — R4..R9 measured the box:
// acc2 (C*K = 128KB/block accumulator state) caps residency at 2 blocks/CU;
// scheduling variations inside that box move +-2%.
template <bool STORE_PARTIALS>
__global__ __launch_bounds__(512, 2)
void vlad_main(const float* __restrict__ x, const uint16_t* __restrict__ wkt,
               const float* __restrict__ bias, float* __restrict__ out,
               float* __restrict__ sum_ws, uint16_t* __restrict__ partials)
{
    const int b = blockIdx.x, slice = blockIdx.y;
    const int cbase = 6 * slice + (slice < 4 ? slice : 4);   // chunk base
    const int nch   = 6 + (slice < 4 ? 1 : 0);               // chunks this block
    const int tid = threadIdx.x;
    const int w    = tid >> 6;       // wave 0..7
    const int lane = tid & 63;
    const int g = lane & 15, q = lane >> 4;
    const int wr = w >> 2;           // C-half for GEMM1; row-half for softmax
    const int wc = w & 3;            // cluster group

    // de-phase the second-resident half of the grid (~4800 cy ~= 2us)
    if (slice >= 16) {
        #pragma unroll
        for (int i = 0; i < 5; ++i) __builtin_amdgcn_s_sleep(15);
    }

    // xs FIRST: tr-read asm assumes LDS offset 0 for xs
    __shared__ __align__(16) uint8_t  xs[2][NBC * 1024];   // 2 x 32KB swizzled bf16
    __shared__ __align__(16) uint16_t assgnT[K_][AP];      // [cluster][row], pitch 80B
    __shared__ __align__(16) float    red1a[16][K_];       // rg0 partial logits (C-half1)
    __shared__ __align__(16) float    red1b[16][K_];       // rg1 partial logits (C-half0)
    __shared__ __align__(16) float    red[NBC][4];         // row softmax sums

    const float* xb = x + (size_t)b * N_ * C_;
    const uint16_t* wp = wkt + (size_t)(wc * 16 + g) * C_ + wr * 256 + q * 8;

    f32x4 acc2[4][4];   // [mf: clusters 16mf..][nf: channels w*64+nf*16..]
    #pragma unroll
    for (int i = 0; i < 4; ++i)
        #pragma unroll
        for (int j = 0; j < 4; ++j)
            acc2[i][j] = (f32x4){0.f, 0.f, 0.f, 0.f};

    float sumA = 0.f;
    const float bias_c = bias[wc * 16 + g];

    // ---- prologue: stage first chunk into xs[0] (32KB, 8 x 4KB) ----
    {
        const int nb0 = cbase * NBC;
        float4 s0[8];
        #pragma unroll
        for (int it = 0; it < 8; ++it) {
            int o  = it * 4096 + tid * 8;
            int n  = o >> 10;
            int sw = ((n & 7) << 4) ^ (((n >> 3) & 1) << 6);
            int c0 = ((o & 1023) ^ sw) >> 1;
            s0[it] = *(const float4*)(xb + (size_t)(nb0 + n) * C_ + c0);
        }
        #pragma unroll
        for (int it = 0; it < 8; ++it) {
            int o = it * 4096 + tid * 8;
            u32x2 p; p[0] = cvt2(s0[it].x, s0[it].y); p[1] = cvt2(s0[it].z, s0[it].w);
            *(u32x2*)(&xs[0][0] + o) = p;
        }
    }

    for (int t = 0; t < nch; ++t) {
        const int cur = t & 1, nxt = cur ^ 1;
        const bool hasNext = (t + 1 < nch);
        const int nb2 = (cbase + t + 1) * NBC;

        float4 stg[8];
        auto issue = [&](int it) {
            int o  = it * 4096 + tid * 8;
            int n  = o >> 10;
            int sw = ((n & 7) << 4) ^ (((n >> 3) & 1) << 6);
            int c0 = ((o & 1023) ^ sw) >> 1;
            stg[it] = *(const float4*)(xb + (size_t)(nb2 + n) * C_ + c0);
        };
        auto wr_stg = [&](int it) {
            int o = it * 4096 + tid * 8;
            u32x2 p; p[0] = cvt2(stg[it].x, stg[it].y); p[1] = cvt2(stg[it].z, stg[it].w);
            *(u32x2*)(&xs[nxt][0] + o) = p;
        };

        // bq loads FIRST (L2 ~200cy), then stg0..3 (HBM): GEMM1's bq
        // consumption waits a counted vmcnt that leaves stg in flight.
        bf16x8 bq[8];
        #pragma unroll
        for (int ks = 0; ks < 8; ++ks)
            bq[ks] = *(const bf16x8*)(wp + ks * 32);

        if (hasNext) { issue(0); issue(1); issue(2); issue(3); }

        bar_lds();   // B0: xs[cur] visible; iter t-1 fully done

        // ---------- GEMM1 (C-split): logits[32 rows][16 clusters] ----------
        f32x4 acc1[2];
        acc1[0] = (f32x4){0.f, 0.f, 0.f, 0.f};
        acc1[1] = (f32x4){0.f, 0.f, 0.f, 0.f};
        __builtin_amdgcn_s_setprio(1);
        #pragma unroll
        for (int ks = 0; ks < 8; ++ks) {
            int off = ((g << 10) + ((wr * 256 + ks * 32 + q * 8) << 1))
                      ^ ((g & 7) << 4) ^ (((g >> 3) & 1) << 6);
            bf16x8 a0 = *(const bf16x8*)(&xs[cur][0] + off);            // rows 0..15
            bf16x8 a1 = *(const bf16x8*)(&xs[cur][0] + off + 16384);    // rows 16..31
            acc1[0] = __builtin_amdgcn_mfma_f32_16x16x32_bf16(a0, bq[ks], acc1[0], 0, 0, 0);
            acc1[1] = __builtin_amdgcn_mfma_f32_16x16x32_bf16(a1, bq[ks], acc1[1], 0, 0, 0);
        }
        __builtin_amdgcn_s_setprio(0);

        if (hasNext) { issue(4); issue(5); issue(6); issue(7); }   // bq dead; regs reused

        // ---------- cross-half exchange: each wr group exports the half it
        // won't softmax (wr1 softmaxes rows 16..31 -> exports rg0, and v.v.)
        if (wr == 1) {
            #pragma unroll
            for (int r = 0; r < 4; ++r)
                red1a[q * 4 + r][wc * 16 + g] = acc1[0][r];   // rg0, C-half1
        } else {
            #pragma unroll
            for (int r = 0; r < 4; ++r)
                red1b[q * 4 + r][wc * 16 + g] = acc1[1][r];   // rg1, C-half0
        }
        bar_lds();   // B1

        // write stg0..3 into xs[nxt] (counted vmcnt wait; loads issued at top)
        if (hasNext) { wr_stg(0); wr_stg(1); wr_stg(2); wr_stg(3); }

        // ---------- split-row softmax: wr0 -> rows 0..15, wr1 -> rows 16..31 ----------
        float ev[4];
        {
            const float* rp = (wr == 0) ? &red1a[0][0] : &red1b[0][0];
            const f32x4  ac = (wr == 0) ? acc1[0] : acc1[1];
            #pragma unroll
            for (int r = 0; r < 4; ++r) {
                float tot = ac[r] + rp[(q * 4 + r) * K_ + wc * 16 + g] + bias_c;
                ev[r] = __expf(tot);
                float s = ev[r];
                s += __shfl_xor(s, 1);
                s += __shfl_xor(s, 2);
                s += __shfl_xor(s, 4);
                s += __shfl_xor(s, 8);
                if (g == 0) red[wr * 16 + q * 4 + r][wc] = s;
            }
        }
        bar_lds();   // B2

        #pragma unroll
        for (int r = 0; r < 4; ++r) {
            int row = wr * 16 + q * 4 + r;
            float4 rv = *(const float4*)red[row];
            float s = (rv.x + rv.y) + (rv.z + rv.w);
            float inv;
            asm("v_rcp_f32 %0, %1" : "=v"(inv) : "v"(s));   // R8-proven accuracy
            float a = ev[r] * inv;
            sumA += a;
            assgnT[wc * 16 + g][row] = (uint16_t)f32_bf16(a);
        }

        // ---------- GEMM2 tr-reads hoisted pre-B3: they read xs[cur] (valid
        // since B0, no WAR — staging writes go to xs[nxt]); B3's lgkm drain
        // doubles as their completion wait ----------
        u32x2 lo[4], hi[4];
        {
            const int nr   = q * 8 + (g >> 2);
            const int swz  = ((nr & 7) << 4) ^ (((nr >> 3) & 1) << 6);
            const int raw0 = (nr << 10) + ((4 * (g & 3)) << 1);
            const int bufb = cur * (NBC * 1024);
            #pragma unroll
            for (int nf = 0; nf < 4; ++nf) {
                int raw = raw0 + ((w * 64 + nf * 16) << 1);
                uint32_t ad1 = (uint32_t)((raw ^ swz) + bufb);
                uint32_t ad2 = ad1 ^ 0x40u;                   // row +4 swizzle flip
                asm volatile("ds_read_b64_tr_b16 %0, %1" : "=v"(lo[nf]) : "v"(ad1));
                asm volatile("ds_read_b64_tr_b16 %0, %1 offset:4096" : "=v"(hi[nf]) : "v"(ad2));
            }
        }
        bar_lds();   // B3: assgnT ready; tr-reads drained

        // ---------- GEMM2: acc2 += assgnT @ x_chunk (full K=32) ----------
        // mf-outer: one live A-frag
        __builtin_amdgcn_s_setprio(1);
        #pragma unroll
        for (int mf = 0; mf < 4; ++mf) {
            bf16x8 afr = *(const bf16x8*)&assgnT[mf * 16 + g][q * 8];
            #pragma unroll
            for (int nf = 0; nf < 4; ++nf) {
                union { struct { u32x2 a, b; } p; bf16x8 v; } fr;
                fr.p.a = lo[nf]; fr.p.b = hi[nf];
                acc2[mf][nf] = __builtin_amdgcn_mfma_f32_16x16x32_bf16(afr, fr.v, acc2[mf][nf], 0, 0, 0);
            }
        }
        __builtin_amdgcn_s_setprio(0);

        // write stg4..7 (loads have had GEMM1-tail + softmax + GEMM2 to land)
        if (hasNext) { wr_stg(4); wr_stg(5); wr_stg(6); wr_stg(7); }
        // next B0 makes xs[nxt] visible
    }

    // ---------- epilogue ----------
    {
        float st = sumA;
        st += __shfl_xor(st, 16);
        st += __shfl_xor(st, 32);
        if (q == 0) atomicAdd(&sum_ws[b * K_ + wc * 16 + g], st);
    }

    if (STORE_PARTIALS) {
        uint16_t* pb = partials + ((size_t)slice * B_ + b) * ((size_t)C_ * K_);
        #pragma unroll
        for (int mf = 0; mf < 4; ++mf)
            #pragma unroll
            for (int nf = 0; nf < 4; ++nf) {
                f32x4 v = acc2[mf][nf];
                u32x2 p; p[0] = cvt2(v[0], v[1]); p[1] = cvt2(v[2], v[3]);
                int chn = w * 64 + nf * 16 + g;
                int cl  = mf * 16 + q * 4;
                __builtin_nontemporal_store(p, (u32x2*)(pb + (size_t)chn * K_ + cl));
            }
    } else {
        float* ob = out + (size_t)b * K_ * C_;
        #pragma unroll
        for (int mf = 0; mf < 4; ++mf)
            #pragma unroll
            for (int nf = 0; nf < 4; ++nf)
                #pragma unroll
                for (int r = 0; r < 4; ++r) {
                    int cluster = mf * 16 + q * 4 + r;
                    int chn = w * 64 + nf * 16 + g;
                    atomicAdd(&ob[(size_t)cluster * C_ + chn], acc2[mf][nf][r]);
                }
    }
}

// ---- reduce partials + subtract centers + /N (parallel-slice, R7) ----
__global__ void vlad_reduce(const uint16_t* __restrict__ partials,
                            const float* __restrict__ sum_ws,
                            const float* __restrict__ centers,
                            float* __restrict__ out)
{
    const int blk = blockIdx.x;          // (b, chn8-group)
    const int b    = blk >> 6;
    const int chn0 = (blk & 63) * 8;
    const int tid = threadIdx.x;
    const int sg  = tid >> 6;            // slice group 0..3
    const int chl = (tid >> 3) & 7;      // chn local 0..7
    const int cl8 = tid & 7;             // cluster-8 group

    __shared__ float lds[4][64][9];      // [sg][cluster][chn], +1 pad

    float acc[8] = {0,0,0,0,0,0,0,0};
    const uint16_t* p = partials + (size_t)b * ((size_t)C_ * K_)
                      + (size_t)(chn0 + chl) * K_ + cl8 * 8;
    #pragma unroll
    for (int s = 0; s < 8; ++s) {        // slices sg, sg+4, ..., sg+28
        bf16x8 v = *(const bf16x8*)(p + (size_t)(sg + s * 4) * ((size_t)B_ * C_ * K_));
        #pragma unroll
        for (int j = 0; j < 8; ++j)
            acc[j] += bf16_f32((uint16_t)v[j]);
    }
    #pragma unroll
    for (int j = 0; j < 8; ++j)
        lds[sg][cl8 * 8 + j][chl] = acc[j];
    __syncthreads();

    const float inv = 1.0f / (float)N_;
    const int chn = tid & 7;
    const int cl  = tid >> 3;            // 0..31
    #pragma unroll
    for (int cc = cl; cc < 64; cc += 32) {
        float r = (lds[0][cc][chn] + lds[1][cc][chn])
                + (lds[2][cc][chn] + lds[3][cc][chn]);
        r = (r - sum_ws[b * K_ + cc] * centers[(size_t)cc * C_ + chn0 + chn]) * inv;
        out[((size_t)b * K_ + cc) * C_ + chn0 + chn] = r;
    }
}

// ---- final for atomic fallback path ----
__global__ void vlad_final(float* __restrict__ out, const float* __restrict__ sum_ws,
                           const float* __restrict__ centers)
{
    int idx = blockIdx.x * blockDim.x + threadIdx.x;
    int c4 = idx & (C_ / 4 - 1);
    int k  = (idx >> 7) & (K_ - 1);
    int b  = idx >> 13;
    float s = sum_ws[b * K_ + k];
    float4 o  = ((float4*)out)[idx];
    float4 ce = ((const float4*)centers)[k * (C_ / 4) + c4];
    const float inv = 1.0f / (float)N_;
    o.x = (o.x - s * ce.x) * inv;
    o.y = (o.y - s * ce.y) * inv;
    o.z = (o.z - s * ce.z) * inv;
    o.w = (o.w - s * ce.w) * inv;
    ((float4*)out)[idx] = o;
}

extern "C" void kernel_launch(void* const* d_in, const int* in_sizes, int n_in,
                              void* d_out, int out_size, void* d_ws, size_t ws_size,
                              hipStream_t stream)
{
    const float* x       = (const float*)d_in[0];
    const float* kern    = (const float*)d_in[1];
    const float* bias    = (const float*)d_in[2];
    const float* centers = (const float*)d_in[3];
    float* out = (float*)d_out;

    uint16_t* wkt    = (uint16_t*)d_ws;
    float*    sum_ws = (float*)((char*)d_ws + SUMWS_OFF);
    uint16_t* parts  = (uint16_t*)((char*)d_ws + PART_OFF);

    prep_wkt<<<(K_ * C_) / 256, 256, 0, stream>>>(kern, wkt, sum_ws);

    if (ws_size >= WS_NEEDED) {
        vlad_main<true><<<dim3(B_, SLICES), 512, 0, stream>>>(x, wkt, bias, out, sum_ws, parts);
        vlad_reduce<<<B_ * (C_ / 8), 256, 0, stream>>>(parts, sum_ws, centers, out);
    } else {
        hipMemsetAsync(out, 0, sizeof(float) * (size_t)B_ * K_ * C_, stream);
        vlad_main<false><<<dim3(B_, SLICES), 512, 0, stream>>>(x, wkt, bias, out, sum_ws, parts);
        vlad_final<<<(B_ * K_ * C_ / 4) / 256, 256, 0, stream>>>(out, sum_ws, centers);
    }
}